// Round 12
// baseline (521.007 us; speedup 1.0000x reference)
//
#include <hip/hip_runtime.h>
#include <math.h>

#define DI __device__ __forceinline__

typedef __attribute__((ext_vector_type(4))) float  f32x4;
typedef __attribute__((ext_vector_type(4))) short  s16x4;
typedef __attribute__((ext_vector_type(8))) short  s16x8;
typedef __attribute__((ext_vector_type(4))) float  ffrag;
typedef s16x8 bfrag;

constexpr int NT = 8192;   // B*S tokens
constexpr int D  = 4096;
constexpr int NE = 8;      // experts
constexpr int KE = 128;    // E * R
constexpr int KX = D + KE; // 4224 extended K

DI short f2bf(float f) {
  unsigned u = __builtin_bit_cast(unsigned, f);
  u += 0x7FFFu + ((u >> 16) & 1u);   // RNE
  return (short)(u >> 16);
}
DI float bf2f(short h) {
  unsigned u = ((unsigned)(unsigned short)h) << 16;
  return __builtin_bit_cast(float, u);
}

#define GLOAD16(gp, lp)                                                        \
  __builtin_amdgcn_global_load_lds(                                            \
      (const __attribute__((address_space(1))) void*)(gp),                     \
      (__attribute__((address_space(3))) void*)(lp), 16, 0, 0)

// ---------------------------------------------------------------- detect (standalone)
__global__ void moe_k_detect(const unsigned* __restrict__ x, int* __restrict__ flag) {
  int l = threadIdx.x;
  int cnt = 0;
  for (int i = l; i < 2048; i += 64) {
    unsigned e = (x[i] >> 23) & 0xFFu;
    cnt += (e >= 110u && e <= 140u) ? 1 : 0;
  }
#pragma unroll
  for (int o = 32; o; o >>= 1) cnt += __shfl_xor(cnt, o);
  if (l == 0) flag[0] = (cnt > 1024) ? 0 : 1;
}

// ---------------------------------------------------------------- prep + xrouter (R5 fused form — measured-best chain)
__global__ __launch_bounds__(256)
void moe_k_prep_xr(const void* __restrict__ wp, const void* __restrict__ lAp,
                   const void* __restrict__ lBp, const void* __restrict__ xp,
                   const void* __restrict__ rp, const int* __restrict__ flag,
                   short* __restrict__ Wb, short* __restrict__ Abt,
                   short* __restrict__ Xb, float* __restrict__ wdense) {
  const bool bf = flag[0] != 0;
  int b = blockIdx.x, t = threadIdx.x;
  if (b < 8192) {
    int tid = b * 256 + t;
    int row = tid >> 9;
    int col = (tid & 511) << 3;
    s16x8 o;
    if (!bf) {
      const float* Wf = (const float*)wp;
      f32x4 v0 = *(const f32x4*)&Wf[(size_t)row * 4096 + col];
      f32x4 v1 = *(const f32x4*)&Wf[(size_t)row * 4096 + col + 4];
      o[0] = f2bf(v0[0]); o[1] = f2bf(v0[1]); o[2] = f2bf(v0[2]); o[3] = f2bf(v0[3]);
      o[4] = f2bf(v1[0]); o[5] = f2bf(v1[1]); o[6] = f2bf(v1[2]); o[7] = f2bf(v1[3]);
    } else {
      o = *(const s16x8*)&((const short*)wp)[(size_t)row * 4096 + col];
    }
    *(s16x8*)&Wb[(size_t)row * KX + col] = o;
  } else if (b < 8208) {
    int d = (b - 8192) * 256 + t;
    for (int j0 = 0; j0 < KE; j0 += 8) {
      s16x8 o;
#pragma unroll
      for (int i = 0; i < 8; ++i) {
        float v = bf ? bf2f(((const short*)lBp)[(size_t)(j0 + i) * 4096 + d])
                     : ((const float*)lBp)[(size_t)(j0 + i) * 4096 + d];
        o[i] = f2bf(2.0f * v);
      }
      *(s16x8*)&Wb[(size_t)d * KX + 4096 + j0] = o;
    }
  } else if (b < 8336) {
    int j = b - 8208;
    int e = j >> 4, r = j & 15;
    for (int d = t; d < 4096; d += 256) {
      size_t src = ((size_t)e * 4096 + d) * 16 + r;
      short v = bf ? ((const short*)lAp)[src] : f2bf(((const float*)lAp)[src]);
      Abt[(size_t)j * 4096 + d] = v;
    }
  } else {
    int wv = t >> 6, l = t & 63;
    int n = (b - 8336) * 4 + wv;
    float acc[NE];
#pragma unroll
    for (int e = 0; e < NE; ++e) acc[e] = 0.f;
    const float* xf = (const float*)xp;
    const short* xh = (const short*)xp;
    const float* rf = (const float*)rp;
    const short* rh = (const short*)rp;
    for (int it = 0; it < 16; ++it) {
      int d = it * 256 + l * 4;
      float x0, x1, x2, x3;
      s16x4 xo;
      if (!bf) {
        f32x4 v = *(const f32x4*)&xf[(size_t)n * D + d];
        x0 = v[0]; x1 = v[1]; x2 = v[2]; x3 = v[3];
        xo[0] = f2bf(x0); xo[1] = f2bf(x1); xo[2] = f2bf(x2); xo[3] = f2bf(x3);
      } else {
        xo = *(const s16x4*)&xh[(size_t)n * D + d];
        x0 = bf2f(xo[0]); x1 = bf2f(xo[1]); x2 = bf2f(xo[2]); x3 = bf2f(xo[3]);
      }
      *(s16x4*)&Xb[(size_t)n * KX + d] = xo;
#pragma unroll
      for (int e = 0; e < NE; ++e) {
        if (!bf) {
          f32x4 w = *(const f32x4*)&rf[(size_t)e * D + d];
          acc[e] += x0 * w[0] + x1 * w[1] + x2 * w[2] + x3 * w[3];
        } else {
          s16x4 w = *(const s16x4*)&rh[(size_t)e * D + d];
          acc[e] += x0 * bf2f(w[0]) + x1 * bf2f(w[1]) + x2 * bf2f(w[2]) + x3 * bf2f(w[3]);
        }
      }
    }
#pragma unroll
    for (int e = 0; e < NE; ++e) {
#pragma unroll
      for (int o = 32; o; o >>= 1) acc[e] += __shfl_xor(acc[e], o);
    }
    float m = acc[0];
#pragma unroll
    for (int e = 1; e < NE; ++e) m = fmaxf(m, acc[e]);
    float p[NE];
#pragma unroll
    for (int e = 0; e < NE; ++e) p[e] = __expf(acc[e] - m);
    int i1 = 0; float v1 = p[0];
#pragma unroll
    for (int e = 1; e < NE; ++e) { if (p[e] > v1) { v1 = p[e]; i1 = e; } }
    int i2 = 0; float v2 = -1.f;
#pragma unroll
    for (int e = 0; e < NE; ++e) { if (e != i1 && p[e] > v2) { v2 = p[e]; i2 = e; } }
    float inv = 1.f / (v1 + v2);
    if (l < NE) {
      float w = (l == i1) ? v1 * inv : ((l == i2) ? v2 * inv : 0.f);
      wdense[(size_t)n * NE + l] = w;
    }
  }
}

// ---------------------------------------------------------------- mid GEMM v2 (R5 verbatim)
__global__ __launch_bounds__(256)
void moe_k_mid2(const short* __restrict__ Xb, const short* __restrict__ Abt,
                const float* __restrict__ wdense, short* __restrict__ XbW) {
  __shared__ __align__(16) short LDS[16384];
  const int t = threadIdx.x, l = t & 63, wv = t >> 6;
  const int wr = wv >> 1, wc = wv & 1;
  const int lr = l & 15, kq = l >> 4;
  const int m0 = (blockIdx.x >> 1) * 64;
  const int j0 = (blockIdx.x & 1) * 64;

  ffrag acc[2][2];
#pragma unroll
  for (int i = 0; i < 2; ++i)
#pragma unroll
    for (int j = 0; j < 2; ++j)
#pragma unroll
      for (int q = 0; q < 4; ++q) acc[i][j][q] = 0.f;

  const int srow = t >> 2, sslot = t & 3;
#define MSTAGE(kt_)                                                            \
  do {                                                                         \
    int _k0 = (kt_) * 32, _b = ((kt_) & 3) * 4096;                             \
    GLOAD16(&Xb[(size_t)(m0 + srow) * KX + _k0 + sslot * 8], &LDS[_b + t * 8]);\
    GLOAD16(&Abt[(size_t)(j0 + srow) * 4096 + _k0 + sslot * 8],                \
            &LDS[_b + 2048 + t * 8]);                                          \
  } while (0)

  MSTAGE(0); MSTAGE(1); MSTAGE(2);
  constexpr int NKT = 128;

  for (int kt = 0; kt < NKT; ++kt) {
    if (kt + 2 < NKT)      asm volatile("s_waitcnt vmcnt(4)" ::: "memory");
    else if (kt + 1 < NKT) asm volatile("s_waitcnt vmcnt(2)" ::: "memory");
    else                   asm volatile("s_waitcnt vmcnt(0)" ::: "memory");
    __builtin_amdgcn_s_barrier();
    __builtin_amdgcn_sched_barrier(0);

    const int bufs = (kt & 3) * 4096;
    const short* As = &LDS[bufs + (wr * 32 + lr) * 32 + kq * 8];
    const short* Bs = &LDS[bufs + 2048 + (wc * 32 + lr) * 32 + kq * 8];
    bfrag a0 = *(const bfrag*)&As[0];
    bfrag a1 = *(const bfrag*)&As[512];
    bfrag b0 = *(const bfrag*)&Bs[0];
    bfrag b1 = *(const bfrag*)&Bs[512];
    if (kt + 3 < NKT) MSTAGE(kt + 3);
    asm volatile("" ::: "memory");
    acc[0][0] = __builtin_amdgcn_mfma_f32_16x16x32_bf16(b0, a0, acc[0][0], 0, 0, 0);
    acc[0][1] = __builtin_amdgcn_mfma_f32_16x16x32_bf16(b1, a0, acc[0][1], 0, 0, 0);
    acc[1][0] = __builtin_amdgcn_mfma_f32_16x16x32_bf16(b0, a1, acc[1][0], 0, 0, 0);
    acc[1][1] = __builtin_amdgcn_mfma_f32_16x16x32_bf16(b1, a1, acc[1][1], 0, 0, 0);
  }

#pragma unroll
  for (int m = 0; m < 2; ++m)
#pragma unroll
    for (int n = 0; n < 2; ++n) {
      int gr = m0 + wr * 32 + m * 16 + lr;
      int jb = j0 + wc * 32 + n * 16 + kq * 4;
      int e  = jb >> 4;
      float w = wdense[(size_t)gr * NE + e];
      s16x4 o;
#pragma unroll
      for (int q = 0; q < 4; ++q) o[q] = f2bf(acc[m][n][q] * w);
      *(s16x4*)&XbW[(size_t)gr * KX + 4096 + jb] = o;
    }
#undef MSTAGE
}

// ---------------------------------------------------------------- main GEMM v7 — 128² tile, 4 blocks/CU (TLP)
// out[n][o] = sum_k Xb[n][k]*Wb[o][k], K=4224. 128x128 tile, BK=32, 256
// threads = 4 waves (2Mx2N), wave-tile 64x64 -> acc[4][4] = 64 AGPR.
// LDS ring-2 = 32KB; combined regs ~110-120 => 4 blocks/CU co-resident
// (16 waves/CU). Mechanism (m114): unsynchronized sibling blocks fill the
// MFMA pipe during each other's barrier/vmcnt stalls — the TLP overlap that
// 1-block/CU barrier-locked schedules (R4/R6/R11) could not create.
// Staging: R3-proven coalesced 64B rows + involution slot^((row>>1)&3)
// (0 conflicts measured). Per tile: barrier_A (WAR: ring-2 overwrite of
// buf kt+1 needs all waves done reading it in tile kt-1); stage(kt+1);
// vmcnt(4) own-loads counted (never 0 mid-loop); barrier_B (publishes all
// waves' residency); 8 frag reads; 16 MFMA with setprio.
__global__ __launch_bounds__(256, 4)
void moe_k_main10(const short* __restrict__ Xb, const short* __restrict__ Wb,
                  const int* __restrict__ flag, void* __restrict__ outp) {
  __shared__ __align__(16) short LDS[16384];  // 32 KiB: 2 x (A 8KB + B 8KB)
  const int t = threadIdx.x;
  const int l = t & 63;
  const int wv = t >> 6;        // 0..3
  const int wr = wv >> 1;       // 0..1 (M half)
  const int wc = wv & 1;        // 0..1 (N half)
  const int lr = l & 15;
  const int kq = l >> 4;

  int wg = blockIdx.x;                        // 2048 wgs, %8==0 -> XCD swizzle
  int swz = (wg & 7) * 256 + (wg >> 3);
  const int tm = (swz >> 5) * 128;            // 64 M blocks
  const int tn = (swz & 31) * 128;            // 32 N blocks

  ffrag acc[4][4];
#pragma unroll
  for (int i = 0; i < 4; ++i)
#pragma unroll
    for (int j = 0; j < 4; ++j)
#pragma unroll
      for (int q = 0; q < 4; ++q) acc[i][j][q] = 0.f;

  // staging: chunk c(0..511) -> row = c>>2, slot = c&3, kc = slot^((row>>1)&3)
#define STG(kt_, OFS_, src_, tb_)                                              \
  do {                                                                         \
    int _k0 = (kt_) * 32, _b = ((kt_) & 1) * 8192 + (OFS_);                    \
    _Pragma("unroll")                                                          \
    for (int _i = 0; _i < 2; ++_i) {                                           \
      int _c = _i * 256 + t;                                                   \
      int _r = _c >> 2;                                                        \
      int _kc = (_c & 3) ^ ((_r >> 1) & 3);                                    \
      GLOAD16(&src_[(size_t)((tb_) + _r) * KX + _k0 + _kc * 8],                \
              &LDS[_b + _c * 8]);                                              \
    }                                                                          \
  } while (0)
#define STAGE_A(kt_) STG(kt_, 0,    Xb, tm)
#define STAGE_B(kt_) STG(kt_, 4096, Wb, tn)

  STAGE_A(0); STAGE_B(0);   // 4 loads/thread

  constexpr int NKT = KX / 32;  // 132
  const int kx = kq ^ ((lr >> 1) & 3);
  const int aofs = (wr * 64 + lr) * 32 + kx * 8;
  const int bofs = 4096 + (wc * 64 + lr) * 32 + kx * 8;

#define MM(m_, n_, bv_, av_)                                                   \
  acc[m_][n_] = __builtin_amdgcn_mfma_f32_16x16x32_bf16(bv_, av_, acc[m_][n_], 0, 0, 0);

  for (int kt = 0; kt < NKT; ++kt) {
    // barrier_A: all waves done reading buf (kt+1)&1 (tile kt-1's data)
    if (kt) __builtin_amdgcn_s_barrier();
    if (kt + 1 < NKT) { STAGE_A(kt + 1); STAGE_B(kt + 1); }
    // own stage(kt) retired (4 newest = stage(kt+1) stay in flight)
    if (kt + 1 < NKT) asm volatile("s_waitcnt vmcnt(4)" ::: "memory");
    else              asm volatile("s_waitcnt vmcnt(0)" ::: "memory");
    // barrier_B: every wave has passed its vmcnt -> tile kt fully resident
    __builtin_amdgcn_s_barrier();
    __builtin_amdgcn_sched_barrier(0);

    const int bufs = (kt & 1) * 8192;
    const short* Ab = &LDS[bufs + aofs];
    const short* Bb = &LDS[bufs + bofs];
    bfrag b0 = *(const bfrag*)&Bb[0];
    bfrag b1 = *(const bfrag*)&Bb[512];
    bfrag b2 = *(const bfrag*)&Bb[1024];
    bfrag b3 = *(const bfrag*)&Bb[1536];
    bfrag a0 = *(const bfrag*)&Ab[0];
    bfrag a1 = *(const bfrag*)&Ab[512];
    bfrag a2 = *(const bfrag*)&Ab[1024];
    bfrag a3 = *(const bfrag*)&Ab[1536];
    __builtin_amdgcn_s_setprio(1);
    MM(0, 0, b0, a0) MM(0, 1, b1, a0) MM(0, 2, b2, a0) MM(0, 3, b3, a0)
    MM(1, 0, b0, a1) MM(1, 1, b1, a1) MM(1, 2, b2, a1) MM(1, 3, b3, a1)
    MM(2, 0, b0, a2) MM(2, 1, b1, a2) MM(2, 2, b2, a2) MM(2, 3, b3, a2)
    MM(3, 0, b0, a3) MM(3, 1, b1, a3) MM(3, 2, b2, a3) MM(3, 3, b3, a3)
    __builtin_amdgcn_s_setprio(0);
  }

  const bool bf = flag[0] != 0;
  float* of = (float*)outp;
  unsigned short* oh = (unsigned short*)outp;
#pragma unroll
  for (int m = 0; m < 4; ++m)
#pragma unroll
    for (int n = 0; n < 4; ++n) {
      int gr = tm + wr * 64 + m * 16 + lr;
      int gc = tn + wc * 64 + n * 16 + kq * 4;
      if (!bf) {
        *(f32x4*)&of[(size_t)gr * D + gc] = acc[m][n];
      } else {
        s16x4 o;
#pragma unroll
        for (int q = 0; q < 4; ++q) o[q] = f2bf(acc[m][n][q]);
        *(s16x4*)&oh[(size_t)gr * D + gc] = o;
      }
    }
#undef STG
#undef STAGE_A
#undef STAGE_B
#undef MM
}

// ---------------------------------------------------------------- host
extern "C" void kernel_launch(void* const* d_in, const int* in_sizes, int n_in,
                              void* d_out, int out_size, void* d_ws, size_t ws_size,
                              hipStream_t stream) {
  const void* x  = d_in[0];
  const void* bw = d_in[1];
  const void* rw = d_in[2];
  const void* lA = d_in[3];
  const void* lB = d_in[4];

  char* ws = (char*)d_ws;
  const size_t XB_BYTES  = (size_t)NT * KX * 2;
  const size_t WB_BYTES  = (size_t)D * KX * 2;
  const size_t ABT_BYTES = (size_t)KE * D * 2;
  const size_t WD_BYTES  = (size_t)NT * NE * 4;
  const size_t NEED = 256 + XB_BYTES + WB_BYTES + ABT_BYTES + WD_BYTES;
  if (ws_size < NEED) return;

  int*   flag   = (int*)ws;
  short* Xb     = (short*)(ws + 256);
  short* Wb     = (short*)(ws + 256 + XB_BYTES);
  short* Abt    = (short*)(ws + 256 + XB_BYTES + WB_BYTES);
  float* wdense = (float*)(ws + 256 + XB_BYTES + WB_BYTES + ABT_BYTES);

  hipLaunchKernelGGL(moe_k_detect, dim3(1), dim3(64), 0, stream,
                     (const unsigned*)x, flag);
  hipLaunchKernelGGL(moe_k_prep_xr, dim3(10384), dim3(256), 0, stream,
                     bw, lA, lB, x, rw, flag, Wb, Abt, Xb, wdense);
  hipLaunchKernelGGL(moe_k_mid2, dim3(256), dim3(256), 0, stream,
                     Xb, Abt, wdense, Xb);
  hipLaunchKernelGGL(moe_k_main10, dim3(2048), dim3(256), 0, stream,
                     Xb, Wb, flag, d_out);
}

// Round 13
// 435.291 us; speedup vs baseline: 1.1969x; 1.1969x over previous
//
#include <hip/hip_runtime.h>
#include <math.h>

#define DI __device__ __forceinline__

typedef __attribute__((ext_vector_type(4))) float  f32x4;
typedef __attribute__((ext_vector_type(4))) short  s16x4;
typedef __attribute__((ext_vector_type(8))) short  s16x8;
typedef __attribute__((ext_vector_type(4))) float  ffrag;
typedef s16x8 bfrag;

constexpr int NT = 8192;   // B*S tokens
constexpr int D  = 4096;
constexpr int NE = 8;      // experts
constexpr int KE = 128;    // E * R
constexpr int KX = D + KE; // 4224 extended K

DI short f2bf(float f) {
  unsigned u = __builtin_bit_cast(unsigned, f);
  u += 0x7FFFu + ((u >> 16) & 1u);   // RNE
  return (short)(u >> 16);
}
DI float bf2f(short h) {
  unsigned u = ((unsigned)(unsigned short)h) << 16;
  return __builtin_bit_cast(float, u);
}

#define GLOAD16(gp, lp)                                                        \
  __builtin_amdgcn_global_load_lds(                                            \
      (const __attribute__((address_space(1))) void*)(gp),                     \
      (__attribute__((address_space(3))) void*)(lp), 16, 0, 0)

// ---------------------------------------------------------------- detect (standalone)
__global__ void moe_k_detect(const unsigned* __restrict__ x, int* __restrict__ flag) {
  int l = threadIdx.x;
  int cnt = 0;
  for (int i = l; i < 2048; i += 64) {
    unsigned e = (x[i] >> 23) & 0xFFu;
    cnt += (e >= 110u && e <= 140u) ? 1 : 0;
  }
#pragma unroll
  for (int o = 32; o; o >>= 1) cnt += __shfl_xor(cnt, o);
  if (l == 0) flag[0] = (cnt > 1024) ? 0 : 1;
}

// ---------------------------------------------------------------- prep + xrouter (R5 fused form — measured-best chain)
__global__ __launch_bounds__(256)
void moe_k_prep_xr(const void* __restrict__ wp, const void* __restrict__ lAp,
                   const void* __restrict__ lBp, const void* __restrict__ xp,
                   const void* __restrict__ rp, const int* __restrict__ flag,
                   short* __restrict__ Wb, short* __restrict__ Abt,
                   short* __restrict__ Xb, float* __restrict__ wdense) {
  const bool bf = flag[0] != 0;
  int b = blockIdx.x, t = threadIdx.x;
  if (b < 8192) {
    int tid = b * 256 + t;
    int row = tid >> 9;
    int col = (tid & 511) << 3;
    s16x8 o;
    if (!bf) {
      const float* Wf = (const float*)wp;
      f32x4 v0 = *(const f32x4*)&Wf[(size_t)row * 4096 + col];
      f32x4 v1 = *(const f32x4*)&Wf[(size_t)row * 4096 + col + 4];
      o[0] = f2bf(v0[0]); o[1] = f2bf(v0[1]); o[2] = f2bf(v0[2]); o[3] = f2bf(v0[3]);
      o[4] = f2bf(v1[0]); o[5] = f2bf(v1[1]); o[6] = f2bf(v1[2]); o[7] = f2bf(v1[3]);
    } else {
      o = *(const s16x8*)&((const short*)wp)[(size_t)row * 4096 + col];
    }
    *(s16x8*)&Wb[(size_t)row * KX + col] = o;
  } else if (b < 8208) {
    int d = (b - 8192) * 256 + t;
    for (int j0 = 0; j0 < KE; j0 += 8) {
      s16x8 o;
#pragma unroll
      for (int i = 0; i < 8; ++i) {
        float v = bf ? bf2f(((const short*)lBp)[(size_t)(j0 + i) * 4096 + d])
                     : ((const float*)lBp)[(size_t)(j0 + i) * 4096 + d];
        o[i] = f2bf(2.0f * v);
      }
      *(s16x8*)&Wb[(size_t)d * KX + 4096 + j0] = o;
    }
  } else if (b < 8336) {
    int j = b - 8208;
    int e = j >> 4, r = j & 15;
    for (int d = t; d < 4096; d += 256) {
      size_t src = ((size_t)e * 4096 + d) * 16 + r;
      short v = bf ? ((const short*)lAp)[src] : f2bf(((const float*)lAp)[src]);
      Abt[(size_t)j * 4096 + d] = v;
    }
  } else {
    int wv = t >> 6, l = t & 63;
    int n = (b - 8336) * 4 + wv;
    float acc[NE];
#pragma unroll
    for (int e = 0; e < NE; ++e) acc[e] = 0.f;
    const float* xf = (const float*)xp;
    const short* xh = (const short*)xp;
    const float* rf = (const float*)rp;
    const short* rh = (const short*)rp;
    for (int it = 0; it < 16; ++it) {
      int d = it * 256 + l * 4;
      float x0, x1, x2, x3;
      s16x4 xo;
      if (!bf) {
        f32x4 v = *(const f32x4*)&xf[(size_t)n * D + d];
        x0 = v[0]; x1 = v[1]; x2 = v[2]; x3 = v[3];
        xo[0] = f2bf(x0); xo[1] = f2bf(x1); xo[2] = f2bf(x2); xo[3] = f2bf(x3);
      } else {
        xo = *(const s16x4*)&xh[(size_t)n * D + d];
        x0 = bf2f(xo[0]); x1 = bf2f(xo[1]); x2 = bf2f(xo[2]); x3 = bf2f(xo[3]);
      }
      *(s16x4*)&Xb[(size_t)n * KX + d] = xo;
#pragma unroll
      for (int e = 0; e < NE; ++e) {
        if (!bf) {
          f32x4 w = *(const f32x4*)&rf[(size_t)e * D + d];
          acc[e] += x0 * w[0] + x1 * w[1] + x2 * w[2] + x3 * w[3];
        } else {
          s16x4 w = *(const s16x4*)&rh[(size_t)e * D + d];
          acc[e] += x0 * bf2f(w[0]) + x1 * bf2f(w[1]) + x2 * bf2f(w[2]) + x3 * bf2f(w[3]);
        }
      }
    }
#pragma unroll
    for (int e = 0; e < NE; ++e) {
#pragma unroll
      for (int o = 32; o; o >>= 1) acc[e] += __shfl_xor(acc[e], o);
    }
    float m = acc[0];
#pragma unroll
    for (int e = 1; e < NE; ++e) m = fmaxf(m, acc[e]);
    float p[NE];
#pragma unroll
    for (int e = 0; e < NE; ++e) p[e] = __expf(acc[e] - m);
    int i1 = 0; float v1 = p[0];
#pragma unroll
    for (int e = 1; e < NE; ++e) { if (p[e] > v1) { v1 = p[e]; i1 = e; } }
    int i2 = 0; float v2 = -1.f;
#pragma unroll
    for (int e = 0; e < NE; ++e) { if (e != i1 && p[e] > v2) { v2 = p[e]; i2 = e; } }
    float inv = 1.f / (v1 + v2);
    if (l < NE) {
      float w = (l == i1) ? v1 * inv : ((l == i2) ? v2 * inv : 0.f);
      wdense[(size_t)n * NE + l] = w;
    }
  }
}

// ---------------------------------------------------------------- mid GEMM v2 (R5 verbatim)
__global__ __launch_bounds__(256)
void moe_k_mid2(const short* __restrict__ Xb, const short* __restrict__ Abt,
                const float* __restrict__ wdense, short* __restrict__ XbW) {
  __shared__ __align__(16) short LDS[16384];
  const int t = threadIdx.x, l = t & 63, wv = t >> 6;
  const int wr = wv >> 1, wc = wv & 1;
  const int lr = l & 15, kq = l >> 4;
  const int m0 = (blockIdx.x >> 1) * 64;
  const int j0 = (blockIdx.x & 1) * 64;

  ffrag acc[2][2];
#pragma unroll
  for (int i = 0; i < 2; ++i)
#pragma unroll
    for (int j = 0; j < 2; ++j)
#pragma unroll
      for (int q = 0; q < 4; ++q) acc[i][j][q] = 0.f;

  const int srow = t >> 2, sslot = t & 3;
#define MSTAGE(kt_)                                                            \
  do {                                                                         \
    int _k0 = (kt_) * 32, _b = ((kt_) & 3) * 4096;                             \
    GLOAD16(&Xb[(size_t)(m0 + srow) * KX + _k0 + sslot * 8], &LDS[_b + t * 8]);\
    GLOAD16(&Abt[(size_t)(j0 + srow) * 4096 + _k0 + sslot * 8],                \
            &LDS[_b + 2048 + t * 8]);                                          \
  } while (0)

  MSTAGE(0); MSTAGE(1); MSTAGE(2);
  constexpr int NKT = 128;

  for (int kt = 0; kt < NKT; ++kt) {
    if (kt + 2 < NKT)      asm volatile("s_waitcnt vmcnt(4)" ::: "memory");
    else if (kt + 1 < NKT) asm volatile("s_waitcnt vmcnt(2)" ::: "memory");
    else                   asm volatile("s_waitcnt vmcnt(0)" ::: "memory");
    __builtin_amdgcn_s_barrier();
    __builtin_amdgcn_sched_barrier(0);

    const int bufs = (kt & 3) * 4096;
    const short* As = &LDS[bufs + (wr * 32 + lr) * 32 + kq * 8];
    const short* Bs = &LDS[bufs + 2048 + (wc * 32 + lr) * 32 + kq * 8];
    bfrag a0 = *(const bfrag*)&As[0];
    bfrag a1 = *(const bfrag*)&As[512];
    bfrag b0 = *(const bfrag*)&Bs[0];
    bfrag b1 = *(const bfrag*)&Bs[512];
    if (kt + 3 < NKT) MSTAGE(kt + 3);
    asm volatile("" ::: "memory");
    acc[0][0] = __builtin_amdgcn_mfma_f32_16x16x32_bf16(b0, a0, acc[0][0], 0, 0, 0);
    acc[0][1] = __builtin_amdgcn_mfma_f32_16x16x32_bf16(b1, a0, acc[0][1], 0, 0, 0);
    acc[1][0] = __builtin_amdgcn_mfma_f32_16x16x32_bf16(b0, a1, acc[1][0], 0, 0, 0);
    acc[1][1] = __builtin_amdgcn_mfma_f32_16x16x32_bf16(b1, a1, acc[1][1], 0, 0, 0);
  }

#pragma unroll
  for (int m = 0; m < 2; ++m)
#pragma unroll
    for (int n = 0; n < 2; ++n) {
      int gr = m0 + wr * 32 + m * 16 + lr;
      int jb = j0 + wc * 32 + n * 16 + kq * 4;
      int e  = jb >> 4;
      float w = wdense[(size_t)gr * NE + e];
      s16x4 o;
#pragma unroll
      for (int q = 0; q < 4; ++q) o[q] = f2bf(acc[m][n][q] * w);
      *(s16x4*)&XbW[(size_t)gr * KX + 4096 + jb] = o;
    }
#undef MSTAGE
}

// ---------------------------------------------------------------- main GEMM v8 — 256x128 tile, 2 blocks/CU
// out[n][o] = sum_k Xb[n][k]*Wb[o][k], K=4224. BM=256, BN=128, BK=32.
// 512 threads = 8 waves (4M x 2N), wave-tile 64x64 -> acc[4][4] = 64 AGPR;
// arch+acc ~120/wave with __launch_bounds__(512,4) -> 16 waves/CU = 2 blocks
// co-resident (R12 proved TLP materializes; R12's failure was 128²-tile
// refetch thrash, not sync). LDS ring-2 = 48KB (2x48=96 <= 160).
// Logical refetch 3.3GB (vs R5 2.2 absorbed->305MB, R12 4.4 thrash->1.18GB);
// 64 live blocks/XCD (vs R12's 256) should keep L2 capture.
// Staging: R3-proven coalesced 64B rows + involution slot^((row>>1)&3).
// Per tile: barrier_A (ring-2 WAR) -> stage(kt+1) 3 loads/thread ->
// counted vmcnt(3) -> barrier_B -> 8 frag reads -> 16 MFMA + setprio.
__global__ __launch_bounds__(512, 4)
void moe_k_main11(const short* __restrict__ Xb, const short* __restrict__ Wb,
                  const int* __restrict__ flag, void* __restrict__ outp) {
  __shared__ __align__(16) short LDS[24576];  // 48 KiB: 2 x (A 16KB + B 8KB)
  const int t = threadIdx.x;
  const int l = t & 63;
  const int wv = t >> 6;        // 0..7
  const int wr = wv >> 1;       // 0..3 (M quarter)
  const int wc = wv & 1;        // 0..1 (N half)
  const int lr = l & 15;
  const int kq = l >> 4;

  int wg = blockIdx.x;                        // 1024 wgs, %8==0 -> XCD swizzle
  int swz = (wg & 7) * 128 + (wg >> 3);
  const int tm = (swz >> 5) * 256;            // 32 M blocks
  const int tn = (swz & 31) * 128;            // 32 N blocks

  ffrag acc[4][4];
#pragma unroll
  for (int i = 0; i < 4; ++i)
#pragma unroll
    for (int j = 0; j < 4; ++j)
#pragma unroll
      for (int q = 0; q < 4; ++q) acc[i][j][q] = 0.f;

  // staging: A 1024 chunks (2/thread), B 512 chunks (1/thread);
  // chunk c -> row = c>>2, slot = c&3, kc = slot^((row>>1)&3)
#define STAGE(kt_)                                                             \
  do {                                                                         \
    int _k0 = (kt_) * 32, _bb = ((kt_) & 1) * 12288;                           \
    _Pragma("unroll")                                                          \
    for (int _i = 0; _i < 2; ++_i) {                                           \
      int _c = _i * 512 + t;                                                   \
      int _r = _c >> 2;                                                        \
      int _kc = (_c & 3) ^ ((_r >> 1) & 3);                                    \
      GLOAD16(&Xb[(size_t)(tm + _r) * KX + _k0 + _kc * 8],                     \
              &LDS[_bb + _c * 8]);                                             \
    }                                                                          \
    {                                                                          \
      int _c = t;                                                              \
      int _r = _c >> 2;                                                        \
      int _kc = (_c & 3) ^ ((_r >> 1) & 3);                                    \
      GLOAD16(&Wb[(size_t)(tn + _r) * KX + _k0 + _kc * 8],                     \
              &LDS[_bb + 8192 + _c * 8]);                                      \
    }                                                                          \
  } while (0)

  STAGE(0);   // 3 loads/thread

  constexpr int NKT = KX / 32;  // 132
  const int kx = kq ^ ((lr >> 1) & 3);
  const int aofs = (wr * 64 + lr) * 32 + kx * 8;
  const int bofs = 8192 + (wc * 64 + lr) * 32 + kx * 8;

#define MM(m_, n_, bv_, av_)                                                   \
  acc[m_][n_] = __builtin_amdgcn_mfma_f32_16x16x32_bf16(bv_, av_, acc[m_][n_], 0, 0, 0);

  for (int kt = 0; kt < NKT; ++kt) {
    // barrier_A: all waves done reading buf (kt+1)&1 (tile kt-1's data)
    if (kt) __builtin_amdgcn_s_barrier();
    if (kt + 1 < NKT) STAGE(kt + 1);
    // own stage(kt) retired (3 newest = stage(kt+1) stay in flight)
    if (kt + 1 < NKT) asm volatile("s_waitcnt vmcnt(3)" ::: "memory");
    else              asm volatile("s_waitcnt vmcnt(0)" ::: "memory");
    // barrier_B: every wave has passed its vmcnt -> tile kt fully resident
    __builtin_amdgcn_s_barrier();
    __builtin_amdgcn_sched_barrier(0);

    const int bufs = (kt & 1) * 12288;
    const short* Ab = &LDS[bufs + aofs];
    const short* Bb = &LDS[bufs + bofs];
    bfrag b0 = *(const bfrag*)&Bb[0];
    bfrag b1 = *(const bfrag*)&Bb[512];
    bfrag b2 = *(const bfrag*)&Bb[1024];
    bfrag b3 = *(const bfrag*)&Bb[1536];
    bfrag a0 = *(const bfrag*)&Ab[0];
    bfrag a1 = *(const bfrag*)&Ab[512];
    bfrag a2 = *(const bfrag*)&Ab[1024];
    bfrag a3 = *(const bfrag*)&Ab[1536];
    __builtin_amdgcn_s_setprio(1);
    MM(0, 0, b0, a0) MM(0, 1, b1, a0) MM(0, 2, b2, a0) MM(0, 3, b3, a0)
    MM(1, 0, b0, a1) MM(1, 1, b1, a1) MM(1, 2, b2, a1) MM(1, 3, b3, a1)
    MM(2, 0, b0, a2) MM(2, 1, b1, a2) MM(2, 2, b2, a2) MM(2, 3, b3, a2)
    MM(3, 0, b0, a3) MM(3, 1, b1, a3) MM(3, 2, b2, a3) MM(3, 3, b3, a3)
    __builtin_amdgcn_s_setprio(0);
  }

  const bool bf = flag[0] != 0;
  float* of = (float*)outp;
  unsigned short* oh = (unsigned short*)outp;
#pragma unroll
  for (int m = 0; m < 4; ++m)
#pragma unroll
    for (int n = 0; n < 4; ++n) {
      int gr = tm + wr * 64 + m * 16 + lr;          // out row
      int gc = tn + wc * 64 + n * 16 + kq * 4;      // out col base
      if (!bf) {
        *(f32x4*)&of[(size_t)gr * D + gc] = acc[m][n];
      } else {
        s16x4 o;
#pragma unroll
        for (int q = 0; q < 4; ++q) o[q] = f2bf(acc[m][n][q]);
        *(s16x4*)&oh[(size_t)gr * D + gc] = o;
      }
    }
#undef STAGE
#undef MM
}

// ---------------------------------------------------------------- host
extern "C" void kernel_launch(void* const* d_in, const int* in_sizes, int n_in,
                              void* d_out, int out_size, void* d_ws, size_t ws_size,
                              hipStream_t stream) {
  const void* x  = d_in[0];
  const void* bw = d_in[1];
  const void* rw = d_in[2];
  const void* lA = d_in[3];
  const void* lB = d_in[4];

  char* ws = (char*)d_ws;
  const size_t XB_BYTES  = (size_t)NT * KX * 2;
  const size_t WB_BYTES  = (size_t)D * KX * 2;
  const size_t ABT_BYTES = (size_t)KE * D * 2;
  const size_t WD_BYTES  = (size_t)NT * NE * 4;
  const size_t NEED = 256 + XB_BYTES + WB_BYTES + ABT_BYTES + WD_BYTES;
  if (ws_size < NEED) return;

  int*   flag   = (int*)ws;
  short* Xb     = (short*)(ws + 256);
  short* Wb     = (short*)(ws + 256 + XB_BYTES);
  short* Abt    = (short*)(ws + 256 + XB_BYTES + WB_BYTES);
  float* wdense = (float*)(ws + 256 + XB_BYTES + WB_BYTES + ABT_BYTES);

  hipLaunchKernelGGL(moe_k_detect, dim3(1), dim3(64), 0, stream,
                     (const unsigned*)x, flag);
  hipLaunchKernelGGL(moe_k_prep_xr, dim3(10384), dim3(256), 0, stream,
                     bw, lA, lB, x, rw, flag, Wb, Abt, Xb, wdense);
  hipLaunchKernelGGL(moe_k_mid2, dim3(256), dim3(256), 0, stream,
                     Xb, Abt, wdense, Xb);
  hipLaunchKernelGGL(moe_k_main11, dim3(1024), dim3(512), 0, stream,
                     Xb, Wb, flag, d_out);
}